// Round 7
// baseline (208.046 us; speedup 1.0000x reference)
//
#include <hip/hip_runtime.h>

// KAN layer fused as one augmented GEMM:
//   out[n][o] = sum_i silu(x[n][i])*scale_base[o][i]
//            + sum_{i,m} basis_m(x[n][i])*scale_sp[o][i]*coef[o][i][m] + bias[o]
// A_aug (8192 x 5376) f16, W_aug (768 x 5376) f16, k = j*768 + i (j=0: silu, j=1..6: basis)
//
// R7 GEMM: 256x192 tile, BK=64, split-K x2 -> grid 256 = 1 block/CU.
// 8 waves 4Mx2N (wave tile 64x96): LDS bytes/FLOP = 2/192+4/256 = 0.026 (was
// 0.0365) -> LDS-read pipe (960 cyc/phase/CU) ~= MFMA pipe (931 cyc/phase/CU).
// A dbuf (2x32KB) + B 3buf (3x24KB) = 136 KB. R5's proven 2-phase schedule:
//   ph0: 10 ds_read | STAGE_A(t+1) | 24 MFMA | lgkmcnt(0) barrier
//   ph1: 10 ds_read | STAGE_B(t+2) | 24 MFMA | lgkmcnt(0) vmcnt(3) barrier
// vmcnt(3): in-flight oldest->newest = B(t+1)[3], A(t+1)[4], B(t+2)[3];
// waiting to 3 drains A(t+1) and B(t+1) (FIFO vmcnt). Epilogue: atomic f32 add
// onto bias-prefilled out (R3-proven recipe).

typedef _Float16 f16;
typedef __attribute__((ext_vector_type(2))) _Float16 f16x2;
typedef __attribute__((ext_vector_type(4))) _Float16 f16x4;
typedef __attribute__((ext_vector_type(8))) _Float16 f16x8;
typedef __attribute__((ext_vector_type(4))) float f32x4;

#define NTOK 8192
#define DIN 768
#define DOUT 768
#define KAUG 5376         // 7*768
#define BM 256
#define BN 192
#define BK 64
#define KHALF (KAUG / 2)  // 2688
#define NT (KHALF / BK)   // 42 K-tiles per block
#define ASZ (BM * BK)     // 16384 f16 = 32 KB
#define BSZ (BN * BK)     // 12288 f16 = 24 KB

typedef __attribute__((address_space(1))) void gvoid;
typedef __attribute__((address_space(3))) void lvoid;

// ---------------- silu + 6 basis values for one x ----------------
__device__ __forceinline__ void spline6(float xv, float* __restrict__ B, float& s) {
  s = xv / (1.0f + __expf(-xv));  // silu
  const float h = 2.0f / 3.0f;
  float Bb[9];
#pragma unroll
  for (int g = 0; g < 9; ++g) {
    float t0 = (float)(g - 3) * h - 1.0f;
    float t1 = (float)(g - 2) * h - 1.0f;
    Bb[g] = (xv >= t0 && xv < t1) ? 1.0f : 0.0f;
  }
#pragma unroll
  for (int p = 1; p <= 3; ++p) {
    float inv = 1.0f / ((float)p * h);
#pragma unroll
    for (int j = 0; j < 8; ++j) {
      if (j < 9 - p) {
        float tj = (float)(j - 3) * h - 1.0f;
        float tjp1 = (float)(j + p + 1 - 3) * h - 1.0f;
        Bb[j] = (xv - tj) * inv * Bb[j] + (tjp1 - xv) * inv * Bb[j + 1];
      }
    }
  }
#pragma unroll
  for (int m = 0; m < 6; ++m) B[m] = Bb[m];
}

#define NBLK_A ((NTOK * DIN) / 1024)  // 6144 (x4-vectorized, 256 thr)
#define NBLK_W ((DOUT * DIN) / 512)   // 1152 (x2-vectorized, 256 thr)

// ---------------- Kernel 1: fused build of A_aug and W_aug ----------------
__global__ __launch_bounds__(256) void build_AW(const float* __restrict__ x,
                                                const float* __restrict__ sb,
                                                const float* __restrict__ ssp,
                                                const float* __restrict__ coef,
                                                f16* __restrict__ Aa,
                                                f16* __restrict__ Wa) {
  const int b = blockIdx.x;
  if (b < NBLK_A) {
    int idx = (b * 256 + threadIdx.x) * 4;  // 4 consecutive i, same n (DIN%4==0)
    float4 xv = *(const float4*)(x + idx);
    int n = idx / DIN;
    int i = idx - n * DIN;

    float B0[6], B1[6], B2[6], B3[6];
    float s0, s1, s2, s3;
    spline6(xv.x, B0, s0);
    spline6(xv.y, B1, s1);
    spline6(xv.z, B2, s2);
    spline6(xv.w, B3, s3);

    size_t base = (size_t)n * KAUG + i;
    f16x4 sv = {(f16)s0, (f16)s1, (f16)s2, (f16)s3};
    *(f16x4*)(Aa + base) = sv;
#pragma unroll
    for (int m = 0; m < 6; ++m) {
      f16x4 bv = {(f16)B0[m], (f16)B1[m], (f16)B2[m], (f16)B3[m]};
      *(f16x4*)(Aa + base + (size_t)(m + 1) * DIN) = bv;
    }
  } else {
    int idx2 = ((b - NBLK_A) * 256 + threadIdx.x) * 2;  // (o,i) and (o,i+1)
    float2 bb = *(const float2*)(sb + idx2);
    float2 pp = *(const float2*)(ssp + idx2);
    int o = idx2 / DIN;
    int i = idx2 - o * DIN;
    size_t base = (size_t)o * KAUG + i;
    f16x2 w0 = {(f16)bb.x, (f16)bb.y};
    *(f16x2*)(Wa + base) = w0;
    float4 c0 = *(const float4*)(coef + (size_t)idx2 * 6);
    float4 c1 = *(const float4*)(coef + (size_t)idx2 * 6 + 4);
    float4 c2 = *(const float4*)(coef + (size_t)idx2 * 6 + 8);
    float ma[6] = {c0.x, c0.y, c0.z, c0.w, c1.x, c1.y};
    float mb[6] = {c1.z, c1.w, c2.x, c2.y, c2.z, c2.w};
#pragma unroll
    for (int m = 0; m < 6; ++m) {
      f16x2 wv = {(f16)(pp.x * ma[m]), (f16)(pp.y * mb[m])};
      *(f16x2*)(Wa + base + (size_t)(m + 1) * DIN) = wv;
    }
  }
}

// ---------------- Kernel 2b: out = bias (broadcast), float4 ----------------
__global__ __launch_bounds__(256) void out_init(const float* __restrict__ bias,
                                                float* __restrict__ out) {
  int idx = blockIdx.x * 256 + threadIdx.x;  // over NTOK*DOUT/4
  ((float4*)out)[idx] = ((const float4*)bias)[idx % (DOUT / 4)];
}

// ---------------- Kernel 3: split-K GEMM, atomic accumulate ----------------
// LDS content: buf[row][slot] = G[row][slot ^ (row&7)] (slot = 8-f16 group).
// global_load_lds dest linear; per-lane GLOBAL source pre-swizzled; reads apply
// the same XOR -> conflict-free (2 lanes per 4-bank group).
__global__ __launch_bounds__(512, 2) void kan_gemm(const f16* __restrict__ A,
                                                   const f16* __restrict__ W,
                                                   float* __restrict__ out) {
  __shared__ alignas(16) f16 As[2 * ASZ];  // 64 KB (double buffer)
  __shared__ alignas(16) f16 Bs[3 * BSZ];  // 72 KB (triple buffer) -> 136 KB

  const int tid = threadIdx.x;
  const int wave = tid >> 6;
  const int lane = tid & 63;

  // bid%8 = XCD. Each XCD: 32 blocks = one K-half x 8 M-panels x 4 N-cols,
  // so its W-half K-window stays L2-resident. Bijective for 256 blocks.
  const int bid = blockIdx.x;
  const int xcd = bid & 7;
  const int wg = xcd * 32 + (bid >> 3);   // 0..255
  const int half = wg >> 7;               // 0,1
  const int rem = wg & 127;
  const int m0 = (rem >> 2) * BM;         // 32 M-panels
  const int n0 = (rem & 3) * BN;          // 4 N-cols
  const size_t k0 = (size_t)half * KHALF;

  const int wm = (wave >> 1) * 64;  // 4 M-waves
  const int wn = (wave & 1) * 96;   // 2 N-waves
  const int r = lane & 15;
  const int q = lane >> 4;
  const int r7 = r & 7;

  f32x4 acc[4][6] = {};  // 96 VGPRs

  // ---- staging source pointers: chunk c = tid + j*512; row = c>>3,
  //      lds slot = c&7, global slot = (c&7) ^ ((c>>3)&7) ----
  const f16* gA[4];
  const f16* gB[3];
#pragma unroll
  for (int j = 0; j < 4; ++j) {
    const int c = tid + j * 512;
    gA[j] = A + (size_t)(m0 + (c >> 3)) * KAUG + k0 + (((c & 7) ^ ((c >> 3) & 7)) * 8);
  }
#pragma unroll
  for (int j = 0; j < 3; ++j) {
    const int c = tid + j * 512;
    gB[j] = W + (size_t)(n0 + (c >> 3)) * KAUG + k0 + (((c & 7) ^ ((c >> 3) & 7)) * 8);
  }
  // wave-uniform LDS dests (f16 units); HW adds lane*16B = lane*8 f16
  // load j dest base = j*4096 + wave*512 within the buffer

#define STAGE_A(bufi, kt)                                                              \
  do {                                                                                 \
    const int ko = (kt)*BK;                                                            \
    f16* ab_ = As + (bufi)*ASZ + wave * 512;                                           \
    _Pragma("unroll") for (int j = 0; j < 4; ++j)                                      \
        __builtin_amdgcn_global_load_lds((gvoid*)(gA[j] + ko),                         \
                                         (lvoid*)(ab_ + j * 4096), 16, 0, 0);          \
  } while (0)

#define STAGE_B(bufi, kt)                                                              \
  do {                                                                                 \
    const int ko = (kt)*BK;                                                            \
    f16* bb_ = Bs + (bufi)*BSZ + wave * 512;                                           \
    _Pragma("unroll") for (int j = 0; j < 3; ++j)                                      \
        __builtin_amdgcn_global_load_lds((gvoid*)(gB[j] + ko),                         \
                                         (lvoid*)(bb_ + j * 4096), 16, 0, 0);          \
  } while (0)

  // one phase: 10 ds_read (kh half) | stage | 24 MFMA
#define PH(Ab, Bb, kh, STAGE_STMT)                                                     \
  do {                                                                                 \
    const int sl = (((kh)*4 + q) ^ r7) * 8;                                            \
    f16x8 af[4], bf[6];                                                                \
    _Pragma("unroll") for (int mi = 0; mi < 4; ++mi) af[mi] =                          \
        *(const f16x8*)&(Ab)[(wm + mi * 16 + r) * BK + sl];                            \
    _Pragma("unroll") for (int ni = 0; ni < 6; ++ni) bf[ni] =                          \
        *(const f16x8*)&(Bb)[(wn + ni * 16 + r) * BK + sl];                            \
    STAGE_STMT;                                                                        \
    __builtin_amdgcn_s_setprio(1);                                                     \
    _Pragma("unroll") for (int mi = 0; mi < 4; ++mi)                                   \
        _Pragma("unroll") for (int ni = 0; ni < 6; ++ni) acc[mi][ni] =                 \
        __builtin_amdgcn_mfma_f32_16x16x32_f16(af[mi], bf[ni], acc[mi][ni], 0, 0, 0);  \
    __builtin_amdgcn_s_setprio(0);                                                     \
  } while (0)

#define MID_BAR()                                                 \
  do {                                                            \
    asm volatile("s_waitcnt lgkmcnt(0)" ::: "memory");            \
    __builtin_amdgcn_sched_barrier(0);                            \
    __builtin_amdgcn_s_barrier();                                 \
  } while (0)

#define FENCE_BAR(VMC)                                                 \
  do {                                                                 \
    asm volatile("s_waitcnt lgkmcnt(0) vmcnt(" #VMC ")" ::: "memory"); \
    __builtin_amdgcn_sched_barrier(0);                                 \
    __builtin_amdgcn_s_barrier();                                      \
  } while (0)

  // prologue: A(0)[4], B(0)[3], B(1)[3]; vmcnt(3) -> A(0),B(0) landed
  STAGE_A(0, 0);
  STAGE_B(0, 0);
  STAGE_B(1, 1);
  asm volatile("s_waitcnt vmcnt(3)" ::: "memory");
  __builtin_amdgcn_sched_barrier(0);
  __builtin_amdgcn_s_barrier();

  for (int t = 0; t < NT; ++t) {  // 42 tiles
    const f16* Ab = As + (t & 1) * ASZ;
    const f16* Bb = Bs + (t % 3) * BSZ;

    // ph0: stage A(t+1) into A-buf (t+1)&1 (not read this tile)
    if (t + 1 < NT) {
      PH(Ab, Bb, 0, STAGE_A((t + 1) & 1, t + 1));
    } else {
      PH(Ab, Bb, 0, (void)0);
    }
    MID_BAR();

    // ph1: stage B(t+2) into B-buf (t+2)%3 (not read this tile)
    if (t + 2 < NT) {
      PH(Ab, Bb, 1, STAGE_B((t + 2) % 3, t + 2));
      FENCE_BAR(3);  // drains A(t+1), B(t+1); leaves B(t+2)[3] in flight
    } else if (t + 1 < NT) {
      PH(Ab, Bb, 1, (void)0);
      FENCE_BAR(0);  // everything (A(t+1), B(t+1)) landed
    } else {
      PH(Ab, Bb, 1, (void)0);  // last tile: no fence, fall to epilogue
    }
  }

#undef STAGE_A
#undef STAGE_B
#undef PH
#undef MID_BAR
#undef FENCE_BAR

  // epilogue: D mapping col = lane&15, row = q*4 + reg; atomic accumulate
#pragma unroll
  for (int mi = 0; mi < 4; ++mi) {
#pragma unroll
    for (int ni = 0; ni < 6; ++ni) {
      const int gcol = n0 + wn + ni * 16 + r;
#pragma unroll
      for (int rg = 0; rg < 4; ++rg) {
        const int grow = m0 + wm + mi * 16 + q * 4 + rg;
        unsafeAtomicAdd(&out[(size_t)grow * DOUT + gcol], acc[mi][ni][rg]);
      }
    }
  }
}

extern "C" void kernel_launch(void* const* d_in, const int* in_sizes, int n_in,
                              void* d_out, int out_size, void* d_ws, size_t ws_size,
                              hipStream_t stream) {
  const float* x = (const float*)d_in[0];           // (4,2048,768)
  const float* coef = (const float*)d_in[1];        // (768,768,6)
  const float* scale_base = (const float*)d_in[2];  // (768,768)
  const float* scale_sp = (const float*)d_in[3];    // (768,768)
  const float* bias = (const float*)d_in[4];        // (768,)
  float* out = (float*)d_out;                       // (8192,768)

  f16* Aa = (f16*)d_ws;                                     // 8192*5376*2 = 88.1 MB
  f16* Wa = (f16*)((char*)d_ws + (size_t)NTOK * KAUG * 2);  // 768*5376*2  = 8.3 MB

  build_AW<<<NBLK_A + NBLK_W, 256, 0, stream>>>(x, scale_base, scale_sp, coef, Aa, Wa);
  out_init<<<(NTOK * DOUT / 4) / 256, 256, 0, stream>>>(bias, out);
  kan_gemm<<<256, 512, 0, stream>>>(Aa, Wa, out);
}

// Round 8
// 191.006 us; speedup vs baseline: 1.0892x; 1.0892x over previous
//
#include <hip/hip_runtime.h>

// KAN layer fused as one augmented GEMM:
//   out[n][o] = sum_i silu(x[n][i])*scale_base[o][i]
//            + sum_{i,m} basis_m(x[n][i])*scale_sp[o][i]*coef[o][i][m] + bias[o]
// A_aug (8192 x 5376) f16, W_aug (768 x 5376) f16, k = j*768 + i (j=0: silu, j=1..6: basis)
//
// R8: GEMM = exact R5 (proven 93.4 us: 128x192, BK=64, 3-buf LDS, 2-phase,
// counted vmcnt(5), setprio, XOR swizzle, XCD swizzle). build_AW rebuilt with
// 16-byte stores (8 i's/thread A-side, 4 i's/thread W-side) -- the non-GEMM
// residual (~95 us/round, never profiled) is the target of this round.

typedef _Float16 f16;
typedef __attribute__((ext_vector_type(4))) _Float16 f16x4;
typedef __attribute__((ext_vector_type(8))) _Float16 f16x8;
typedef __attribute__((ext_vector_type(4))) float f32x4;

#define NTOK 8192
#define DIN 768
#define DOUT 768
#define KAUG 5376        // 7*768
#define BM 128
#define BN 192
#define BK 64
#define NKT (KAUG / BK)  // 84 K-tiles
#define ASZ (BM * BK)    // 8192 f16 = 16 KB
#define BSZ (BN * BK)    // 12288 f16 = 24 KB
#define NBLK ((NTOK / BM) * (DOUT / BN))  // 64*4 = 256 blocks

typedef __attribute__((address_space(1))) void gvoid;
typedef __attribute__((address_space(3))) void lvoid;

// ---------------- silu + 6 basis values for one x ----------------
__device__ __forceinline__ void spline6(float xv, float* __restrict__ B, float& s) {
  s = xv / (1.0f + __expf(-xv));  // silu
  const float h = 2.0f / 3.0f;
  float Bb[9];
#pragma unroll
  for (int g = 0; g < 9; ++g) {
    float t0 = (float)(g - 3) * h - 1.0f;
    float t1 = (float)(g - 2) * h - 1.0f;
    Bb[g] = (xv >= t0 && xv < t1) ? 1.0f : 0.0f;
  }
#pragma unroll
  for (int p = 1; p <= 3; ++p) {
    float inv = 1.0f / ((float)p * h);
#pragma unroll
    for (int j = 0; j < 8; ++j) {
      if (j < 9 - p) {
        float tj = (float)(j - 3) * h - 1.0f;
        float tjp1 = (float)(j + p + 1 - 3) * h - 1.0f;
        Bb[j] = (xv - tj) * inv * Bb[j] + (tjp1 - xv) * inv * Bb[j + 1];
      }
    }
  }
#pragma unroll
  for (int m = 0; m < 6; ++m) B[m] = Bb[m];
}

#define NBLK_A ((NTOK * DIN) / 2048)  // 3072 blocks (8 i's per thread)
#define NBLK_W ((DOUT * DIN) / 1024)  // 576 blocks  (4 i's per thread)

// ---------------- Kernel 1: fused build of A_aug and W_aug, 16B stores ----------------
__global__ __launch_bounds__(256) void build_AW(const float* __restrict__ x,
                                                const float* __restrict__ sb,
                                                const float* __restrict__ ssp,
                                                const float* __restrict__ coef,
                                                f16* __restrict__ Aa,
                                                f16* __restrict__ Wa) {
  const int b = blockIdx.x;
  if (b < NBLK_A) {
    // 8 consecutive i per thread; 768 % 8 == 0 -> all 8 share the same n
    int idx = (b * 256 + threadIdx.x) * 8;
    float4 x0 = *(const float4*)(x + idx);
    float4 x1 = *(const float4*)(x + idx + 4);
    float xs[8] = {x0.x, x0.y, x0.z, x0.w, x1.x, x1.y, x1.z, x1.w};
    int n = idx / DIN;
    int i = idx - n * DIN;

    float Bv[8][6], sv[8];
#pragma unroll
    for (int t = 0; t < 8; ++t) spline6(xs[t], Bv[t], sv[t]);

    size_t base = (size_t)n * KAUG + i;  // 16B-aligned (5376%8==0, i%8==0)
    f16x8 s8;
#pragma unroll
    for (int t = 0; t < 8; ++t) s8[t] = (f16)sv[t];
    *(f16x8*)(Aa + base) = s8;
#pragma unroll
    for (int m = 0; m < 6; ++m) {
      f16x8 b8;
#pragma unroll
      for (int t = 0; t < 8; ++t) b8[t] = (f16)Bv[t][m];
      *(f16x8*)(Aa + base + (size_t)(m + 1) * DIN) = b8;
    }
  } else {
    // 4 consecutive i per thread; 768 % 4 == 0 -> same o
    int idx = ((b - NBLK_A) * 256 + threadIdx.x) * 4;
    float4 bb = *(const float4*)(sb + idx);
    float4 pp = *(const float4*)(ssp + idx);
    int o = idx / DIN;
    int i = idx - o * DIN;
    size_t base = (size_t)o * KAUG + i;  // 8B-aligned
    f16x4 w0 = {(f16)bb.x, (f16)bb.y, (f16)bb.z, (f16)bb.w};
    *(f16x4*)(Wa + base) = w0;
    // coef rows for the 4 edges: 24 consecutive floats, float4-aligned
    float c[24];
#pragma unroll
    for (int j = 0; j < 6; ++j) {
      float4 cv = *(const float4*)(coef + (size_t)idx * 6 + j * 4);
      c[j * 4 + 0] = cv.x; c[j * 4 + 1] = cv.y; c[j * 4 + 2] = cv.z; c[j * 4 + 3] = cv.w;
    }
    float sp[4] = {pp.x, pp.y, pp.z, pp.w};
#pragma unroll
    for (int m = 0; m < 6; ++m) {
      f16x4 wv = {(f16)(sp[0] * c[0 * 6 + m]), (f16)(sp[1] * c[1 * 6 + m]),
                  (f16)(sp[2] * c[2 * 6 + m]), (f16)(sp[3] * c[3 * 6 + m])};
      *(f16x4*)(Wa + base + (size_t)(m + 1) * DIN) = wv;
    }
  }
}

// ---------------- Kernel 2: GEMM C = A_aug * W_aug^T + bias (exact R5) ----------------
// LDS content: buf[row][slot] = G[row][slot ^ (row&7)] (slot = 8-f16 group of K).
// global_load_lds dest linear (chunk c -> 16B at c*16); per-lane GLOBAL src is
// pre-swizzled. Reads apply the same XOR -> conflict-free.
// Schedule per K-tile t (3-buf: prefetch target never concurrently read):
//   ph0: ds_read af/bf[kh=0] | stage B(t+2) | 12 MFMA | lgkmcnt(0) barrier
//   ph1: ds_read af/bf[kh=1] | stage A(t+2) | 12 MFMA | lgkmcnt(0) vmcnt(5) barrier
__global__ __launch_bounds__(512, 2) void kan_gemm(const f16* __restrict__ A,
                                                   const f16* __restrict__ W,
                                                   const float* __restrict__ bias,
                                                   float* __restrict__ out) {
  __shared__ alignas(16) f16 As[3 * ASZ];  // 48 KB
  __shared__ alignas(16) f16 Bs[3 * BSZ];  // 72 KB  (120 KB total, 1 block/CU)

  const int tid = threadIdx.x;
  const int wave = tid >> 6;
  const int lane = tid & 63;

  // XCD-chunked swizzle: 256 % 8 == 0 -> bijective. Each XCD: 8 M-panels x 4 cols.
  const int bid = blockIdx.x;
  const int wg = (bid & 7) * (NBLK / 8) + (bid >> 3);
  const int m0 = (wg >> 2) * BM;
  const int n0 = (wg & 3) * BN;

  const int wm = (wave >> 2) * 64;  // 2 M-waves
  const int wn = (wave & 3) * 48;   // 4 N-waves
  const int r = lane & 15;
  const int q = lane >> 4;
  const int r7 = r & 7;

  f32x4 acc[4][3] = {};

  // ---- staging source pointers (chunk c: row = c>>3, lds slot = c&7,
  //      global slot = (c&7) ^ (row&7)) ----
  const int cA0 = tid, cA1 = tid + 512;
  const int cB0 = tid, cB1 = tid + 512, cB2 = tid + 1024;
  const f16* gA0 = A + (size_t)(m0 + (cA0 >> 3)) * KAUG + ((cA0 & 7) ^ ((cA0 >> 3) & 7)) * 8;
  const f16* gA1 = A + (size_t)(m0 + (cA1 >> 3)) * KAUG + ((cA1 & 7) ^ ((cA1 >> 3) & 7)) * 8;
  const f16* gB0 = W + (size_t)(n0 + (cB0 >> 3)) * KAUG + ((cB0 & 7) ^ ((cB0 >> 3) & 7)) * 8;
  const f16* gB1 = W + (size_t)(n0 + (cB1 >> 3)) * KAUG + ((cB1 & 7) ^ ((cB1 >> 3) & 7)) * 8;
  const f16* gB2 = W + (size_t)(n0 + (cB2 >> 3)) * KAUG + ((cB2 & 7) ^ ((cB2 >> 3) & 7)) * 8;
  // wave-uniform LDS dests (f16 units); HW adds lane*16B
  const int dA0 = wave * 512, dA1 = 4096 + wave * 512;
  const int dB0 = wave * 512, dB1 = 4096 + wave * 512, dB2 = 8192 + wave * 512;

#define STAGE_B(bufi, kt)                                                                  \
  do {                                                                                     \
    const int ko = (kt)*BK;                                                                \
    f16* bb_ = Bs + (bufi)*BSZ;                                                            \
    __builtin_amdgcn_global_load_lds((gvoid*)(gB0 + ko), (lvoid*)(bb_ + dB0), 16, 0, 0);   \
    __builtin_amdgcn_global_load_lds((gvoid*)(gB1 + ko), (lvoid*)(bb_ + dB1), 16, 0, 0);   \
    __builtin_amdgcn_global_load_lds((gvoid*)(gB2 + ko), (lvoid*)(bb_ + dB2), 16, 0, 0);   \
  } while (0)

#define STAGE_A(bufi, kt)                                                                  \
  do {                                                                                     \
    const int ko = (kt)*BK;                                                                \
    f16* ab_ = As + (bufi)*ASZ;                                                            \
    __builtin_amdgcn_global_load_lds((gvoid*)(gA0 + ko), (lvoid*)(ab_ + dA0), 16, 0, 0);   \
    __builtin_amdgcn_global_load_lds((gvoid*)(gA1 + ko), (lvoid*)(ab_ + dA1), 16, 0, 0);   \
  } while (0)

  // one phase: ds_read the kh-half subtile, issue stage, MFMA cluster
#define PH(bufi, kh, STAGE_STMT)                                                           \
  do {                                                                                     \
    const f16* Ab = As + (bufi)*ASZ;                                                       \
    const f16* Bb = Bs + (bufi)*BSZ;                                                       \
    const int sl = (((kh)*4 + q) ^ r7) * 8;                                                \
    f16x8 af[4], bf[3];                                                                    \
    _Pragma("unroll") for (int mi = 0; mi < 4; ++mi) af[mi] =                              \
        *(const f16x8*)&Ab[(wm + mi * 16 + r) * BK + sl];                                  \
    _Pragma("unroll") for (int ni = 0; ni < 3; ++ni) bf[ni] =                              \
        *(const f16x8*)&Bb[(wn + ni * 16 + r) * BK + sl];                                  \
    STAGE_STMT;                                                                            \
    __builtin_amdgcn_s_setprio(1);                                                         \
    _Pragma("unroll") for (int mi = 0; mi < 4; ++mi)                                       \
        _Pragma("unroll") for (int ni = 0; ni < 3; ++ni) acc[mi][ni] =                     \
        __builtin_amdgcn_mfma_f32_16x16x32_f16(af[mi], bf[ni], acc[mi][ni], 0, 0, 0);      \
    __builtin_amdgcn_s_setprio(0);                                                         \
  } while (0)

  // end-of-iteration fence: ds_reads of this iter complete + staged tile t+1
  // landed (counted vmcnt, never 0 in loop), then barrier.
#define FENCE_BAR(VMC)                                            \
  do {                                                            \
    asm volatile("s_waitcnt lgkmcnt(0) vmcnt(" #VMC ")" ::: "memory"); \
    __builtin_amdgcn_sched_barrier(0);                            \
    __builtin_amdgcn_s_barrier();                                 \
  } while (0)

#define MID_BAR()                                                 \
  do {                                                            \
    asm volatile("s_waitcnt lgkmcnt(0)" ::: "memory");            \
    __builtin_amdgcn_sched_barrier(0);                            \
    __builtin_amdgcn_s_barrier();                                 \
  } while (0)

  // prologue: stage tiles 0 and 1 (issue order matters for vmcnt accounting)
  STAGE_B(0, 0);
  STAGE_A(0, 0);
  STAGE_B(1, 1);
  STAGE_A(1, 1);
  FENCE_BAR(5);  // tile 0 fully landed (5 newest = tile 1's loads)

  for (int t = 0; t < NKT - 2; ++t) {  // t = 0..81, stages t+2 in [2,83]
    const int rb = t % 3;
    const int pb = (t + 2) % 3;
    PH(rb, 0, STAGE_B(pb, t + 2));
    MID_BAR();
    PH(rb, 1, STAGE_A(pb, t + 2));
    FENCE_BAR(5);  // tile t+1 fully landed
  }
  {  // t = 82: no staging; drain for final tile
    const int rb = (NKT - 2) % 3;
    PH(rb, 0, (void)0);
    MID_BAR();
    PH(rb, 1, (void)0);
    FENCE_BAR(0);
  }
  {  // t = 83
    const int rb = (NKT - 1) % 3;
    PH(rb, 0, (void)0);
    PH(rb, 1, (void)0);
  }

#undef STAGE_A
#undef STAGE_B
#undef PH
#undef FENCE_BAR
#undef MID_BAR

  // epilogue: D mapping col = lane&15, row = q*4 + reg; bias fused
#pragma unroll
  for (int mi = 0; mi < 4; ++mi) {
#pragma unroll
    for (int ni = 0; ni < 3; ++ni) {
      const int gcol = n0 + wn + ni * 16 + r;
      const float bv = bias[gcol];
#pragma unroll
      for (int rg = 0; rg < 4; ++rg) {
        const int grow = m0 + wm + mi * 16 + q * 4 + rg;
        out[(size_t)grow * DOUT + gcol] = acc[mi][ni][rg] + bv;
      }
    }
  }
}

extern "C" void kernel_launch(void* const* d_in, const int* in_sizes, int n_in,
                              void* d_out, int out_size, void* d_ws, size_t ws_size,
                              hipStream_t stream) {
  const float* x = (const float*)d_in[0];           // (4,2048,768)
  const float* coef = (const float*)d_in[1];        // (768,768,6)
  const float* scale_base = (const float*)d_in[2];  // (768,768)
  const float* scale_sp = (const float*)d_in[3];    // (768,768)
  const float* bias = (const float*)d_in[4];        // (768,)
  float* out = (float*)d_out;                       // (8192,768)

  f16* Aa = (f16*)d_ws;                                     // 8192*5376*2 = 88.1 MB
  f16* Wa = (f16*)((char*)d_ws + (size_t)NTOK * KAUG * 2);  // 768*5376*2  = 8.3 MB

  build_AW<<<NBLK_A + NBLK_W, 256, 0, stream>>>(x, scale_base, scale_sp, coef, Aa, Wa);
  kan_gemm<<<NBLK, 512, 0, stream>>>(Aa, Wa, bias, out);
}